// Round 6
// baseline (535.849 us; speedup 1.0000x reference)
//
#include <hip/hip_runtime.h>

typedef __attribute__((ext_vector_type(8))) _Float16 half8;
typedef __attribute__((ext_vector_type(4))) _Float16 half4;
typedef __attribute__((ext_vector_type(4))) float f32x4;
typedef __attribute__((ext_vector_type(16))) float f32x16;

#define CDIM 256
#define NDIM 4096
#define MFMAH(a, b, c) __builtin_amdgcn_mfma_f32_16x16x32_f16((a), (b), (c), 0, 0, 0)
#define MFMA32(a, b, c) __builtin_amdgcn_mfma_f32_32x32x16_f16((a), (b), (c), 0, 0, 0)

// ---------------------------------------------------------------------------
// Cast W matrices to fp16 once per launch (L2-resident afterwards).
// ---------------------------------------------------------------------------
__global__ void cast_w_kernel(const float* __restrict__ Wq,
                              const float* __restrict__ Wk,
                              const float* __restrict__ Wv,
                              _Float16* __restrict__ Wc) {
  int t = blockIdx.x * 256 + threadIdx.x;      // 49152 float4 groups total
  int mat = t >> 14;                            // /16384
  int idx = (t & 16383) * 4;
  const float* W = (mat == 0) ? Wq : (mat == 1 ? Wk : Wv);
  float4 w = *(const float4*)(W + idx);
  half4 h = {(_Float16)w.x, (_Float16)w.y, (_Float16)w.z, (_Float16)w.w};
  *(half4*)(Wc + mat * 65536 + idx) = h;
}

// ---------------------------------------------------------------------------
// Projection: Y[b,o,n] = sum_c W[o,c] X[b,c,n] + bias[o]
// n-tile 128, full o (256). X staged once. Staging: each thread gathers 8
// c-values of ONE n (coalesced b32 loads) -> one bank-balanced ds_write_b128
// (old per-element b16 writes were 16-32-way bank-conflicted).
// ---------------------------------------------------------------------------
__global__ __launch_bounds__(256, 2) void proj_kernel(
    const float* __restrict__ queries, const float* __restrict__ keys,
    const _Float16* __restrict__ Wc,
    const float* __restrict__ bq, const float* __restrict__ bk,
    const float* __restrict__ bv,
    _Float16* __restrict__ Qh, _Float16* __restrict__ Kh,
    _Float16* __restrict__ Vh)
{
  const int z = blockIdx.z, p = z >> 3, b = z & 7;
  const float* __restrict__ X = (p == 0) ? queries : keys;
  const _Float16* __restrict__ W = Wc + p * 65536;
  const float* __restrict__ bias = (p == 0) ? bq : (p == 1 ? bk : bv);
  const int n0 = blockIdx.x * 128;

  __shared__ __align__(16) _Float16 Xs[128][264];  // [n][c], 528 B rows

  const int tid = threadIdx.x;
  const int wv = tid >> 6, lane = tid & 63, l16 = lane & 15, quad = lane >> 4;

  // stage X tile 128n x 256c: thread (nn, ch) gathers 8 c for its n
  {
    const int nn = tid & 127, ch = tid >> 7;
#pragma unroll
    for (int it2 = 0; it2 < 16; ++it2) {
      const int c0 = it2 * 16 + ch * 8;
      const float* src = X + ((size_t)(b * CDIM + c0)) * NDIM + n0 + nn;
      half8 hx;
#pragma unroll
      for (int k = 0; k < 8; ++k) hx[k] = (_Float16)src[(size_t)k * NDIM];
      *(half8*)&Xs[nn][c0] = hx;
    }
  }
  __syncthreads();

  f32x4 acc[4][8];
#pragma unroll
  for (int og = 0; og < 4; ++og)
#pragma unroll
    for (int ng = 0; ng < 8; ++ng) acc[og][ng] = (f32x4){0.f, 0.f, 0.f, 0.f};

#pragma unroll
  for (int kc = 0; kc < 8; ++kc) {
    half8 wf[4], xf[8];
#pragma unroll
    for (int og = 0; og < 4; ++og)
      wf[og] = *(const half8*)(W + (wv * 64 + og * 16 + l16) * CDIM + kc * 32 + quad * 8);
#pragma unroll
    for (int ng = 0; ng < 8; ++ng)
      xf[ng] = *(const half8*)&Xs[ng * 16 + l16][kc * 32 + quad * 8];
#pragma unroll
    for (int og = 0; og < 4; ++og)
#pragma unroll
      for (int ng = 0; ng < 8; ++ng)
        acc[og][ng] = MFMAH(wf[og], xf[ng], acc[og][ng]);
  }

  // epilogue: D rows = o (quad*4+r), cols = n (l16)
#pragma unroll
  for (int og = 0; og < 4; ++og) {
    float4 b4 = *(const float4*)&bias[wv * 64 + og * 16 + quad * 4];
#pragma unroll
    for (int ng = 0; ng < 8; ++ng) {
      const int n = n0 + ng * 16 + l16;
      if (p == 2) {
#pragma unroll
        for (int r = 0; r < 4; ++r) {
          int o = wv * 64 + og * 16 + quad * 4 + r;
          float y = acc[og][ng][r] + ((const float*)&b4)[r];
          Vh[((size_t)(b * CDIM + o)) * NDIM + n] = (_Float16)y;
        }
      } else {
        half4 h4;
#pragma unroll
        for (int r = 0; r < 4; ++r)
          h4[r] = (_Float16)(acc[og][ng][r] + ((const float*)&b4)[r]);
        size_t idx = ((size_t)(b * NDIM + n)) * CDIM + wv * 64 + og * 16 + quad * 4;
        if (p == 0) *(half4*)&Qh[idx] = h4;
        else        *(half4*)&Kh[idx] = h4;
      }
    }
  }
}

// ---------------------------------------------------------------------------
// Flash attention. QK^T via 32x32x16 MFMA quadrants: wave (jq,iq) computes
// S^T[32j x 32i] -> kf A-frag reads halved vs 16x16 scheme. Softmax combines
// the two jq halves via LDS partials (Mp/Sp). PV unchanged (16x16, Ps
// round-trip, 4x V-frag reuse).
// ---------------------------------------------------------------------------
__global__ __launch_bounds__(256, 2) void attn_kernel(
    const float* __restrict__ queries, const float* __restrict__ mask,
    const _Float16* __restrict__ Qh, const _Float16* __restrict__ Kh,
    const _Float16* __restrict__ Vh, float* __restrict__ out)
{
  const int blk = blockIdx.x, b = blk & 7, it = blk >> 3;  // b=blk&7: XCD L2 locality
  const int i0 = it * 64;

  __shared__ __align__(16) _Float16 Ks[64][264];  // [j][c]  33792 B
  __shared__ __align__(16) _Float16 Vs[256][72];  // [c][j]  36864 B
  __shared__ __align__(16) _Float16 Ps[64][72];   // [i][j]   9216 B
  __shared__ __align__(16) float Al[64];          // alpha per i-row
  __shared__ __align__(16) float Li[64];          // 1/l per i-row
  __shared__ __align__(16) float Mp[2][64];       // per-jq partial max
  __shared__ __align__(16) float Sp[2][64];       // per-jq partial sum

  const int tid = threadIdx.x;
  const int wv = tid >> 6, lane = tid & 63, l16 = lane & 15, quad = lane >> 4;
  const int l32 = lane & 31, h = lane >> 5;
  const int jq = wv & 1, iq = wv >> 1;
  const int myi = iq * 32 + l32;   // this lane's i-row (QK/softmax role)

  // Q-frags, 32x32x16 B-operand layout: n = lane&31 = i, k = h*8 + t
  half8 qf[16];
  {
    const size_t qrow = ((size_t)(b * NDIM + i0 + myi)) * CDIM;
#pragma unroll
    for (int kk = 0; kk < 16; ++kk)
      qf[kk] = *(const half8*)(Qh + qrow + kk * 16 + h * 8);
  }
  const float mval = mask[(size_t)b * NDIM + i0 + myi];
  float m_run = -1e30f, l_run = 0.f;

  f32x4 O[4][4];  // PV accumulator: [i-group][ch-group], wave's ch base = wv*64
#pragma unroll
  for (int g = 0; g < 4; ++g)
#pragma unroll
    for (int cg = 0; cg < 4; ++cg) O[g][cg] = (f32x4){0.f, 0.f, 0.f, 0.f};

  const _Float16* __restrict__ Kb = Kh + (size_t)b * NDIM * CDIM;
  const _Float16* __restrict__ Vbp = Vh + (size_t)b * CDIM * NDIM;

  for (int jt = 0; jt < 64; ++jt) {
    const int j0 = jt * 64;
    __syncthreads();  // prev iter's Ks/Vs/Ps reads complete
#pragma unroll
    for (int it2 = 0; it2 < 8; ++it2) {
      int id = tid + it2 * 256;
      int j = id >> 5, c8 = id & 31;
      *(uint4*)&Ks[j][c8 * 8] = *(const uint4*)(Kb + (size_t)(j0 + j) * CDIM + c8 * 8);
    }
#pragma unroll
    for (int it2 = 0; it2 < 8; ++it2) {
      int id = tid + it2 * 256;
      int c = id >> 3, j8 = id & 7;
      *(uint4*)&Vs[c][j8 * 8] = *(const uint4*)(Vbp + (size_t)c * NDIM + j0 + j8 * 8);
    }
    __syncthreads();

    // S^T quadrant: D[m=j (jq half)][n=i (iq half)], 16 regs
    f32x16 st = {};
#pragma unroll
    for (int kk = 0; kk < 16; ++kk) {
      half8 kf = *(const half8*)&Ks[jq * 32 + l32][kk * 16 + h * 8];
      st = MFMA32(kf, qf[kk], st);
    }

    // local max over this lane's 16 j (+ xor32 for the 4h-offset rows)
    float mx = -1e30f;
#pragma unroll
    for (int r = 0; r < 16; ++r) mx = fmaxf(mx, st[r] * mval);
    mx = fmaxf(mx, __shfl_xor(mx, 32));
    if (h == 0) Mp[jq][myi] = mx;
    __syncthreads();  // barrier A: partial maxima visible

    const float mxall = fmaxf(Mp[0][myi], Mp[1][myi]);
    const float mnew = fmaxf(m_run, mxall);
    const float alpha = __expf(m_run - mnew);
    m_run = mnew;
    if (jq == 0 && h == 0) Al[myi] = alpha;

    float psum = 0.f;
#pragma unroll
    for (int g2 = 0; g2 < 4; ++g2) {
      // j = jq*32 + 8*g2 + 4*h + r  (r = reg&3) -> contiguous half4
      float p0 = __expf(st[g2 * 4 + 0] * mval - mnew);
      float p1 = __expf(st[g2 * 4 + 1] * mval - mnew);
      float p2 = __expf(st[g2 * 4 + 2] * mval - mnew);
      float p3 = __expf(st[g2 * 4 + 3] * mval - mnew);
      psum += (p0 + p1) + (p2 + p3);
      half4 hp = {(_Float16)p0, (_Float16)p1, (_Float16)p2, (_Float16)p3};
      *(half4*)&Ps[myi][jq * 32 + g2 * 8 + h * 4] = hp;
    }
    psum += __shfl_xor(psum, 32);
    if (h == 0) Sp[jq][myi] = psum;
    __syncthreads();  // barrier B: Ps/Sp/Al visible

    l_run = l_run * alpha + Sp[0][myi] + Sp[1][myi];

    // O rescale + O += P V  (wave covers all 64 i, channels [wv*64, +64))
    f32x4 av[4];
#pragma unroll
    for (int g = 0; g < 4; ++g) av[g] = *(const f32x4*)&Al[g * 16 + quad * 4];
#pragma unroll
    for (int g = 0; g < 4; ++g)
#pragma unroll
      for (int cg = 0; cg < 4; ++cg)
#pragma unroll
        for (int r = 0; r < 4; ++r) O[g][cg][r] *= av[g][r];
#pragma unroll
    for (int kk = 0; kk < 2; ++kk) {
      half8 pa[4], vf[4];
#pragma unroll
      for (int g = 0; g < 4; ++g)
        pa[g] = *(const half8*)&Ps[g * 16 + l16][kk * 32 + quad * 8];
#pragma unroll
      for (int cg = 0; cg < 4; ++cg)
        vf[cg] = *(const half8*)&Vs[wv * 64 + cg * 16 + l16][kk * 32 + quad * 8];
#pragma unroll
      for (int g = 0; g < 4; ++g)
#pragma unroll
        for (int cg = 0; cg < 4; ++cg)
          O[g][cg] = MFMAH(pa[g], vf[cg], O[g][cg]);
    }
  }

  // publish 1/l, then blended epilogue
  if (jq == 0 && h == 0) Li[myi] = 1.0f / l_run;
  __syncthreads();
#pragma unroll
  for (int g = 0; g < 4; ++g) {
    f32x4 li4 = *(const f32x4*)&Li[g * 16 + quad * 4];
    const int i = i0 + g * 16 + quad * 4;
    float4 m4 = *(const float4*)&mask[(size_t)b * NDIM + i];
#pragma unroll
    for (int cg = 0; cg < 4; ++cg) {
      const int c = wv * 64 + cg * 16 + l16;
      const size_t base = ((size_t)(b * CDIM + c)) * NDIM + i;
      float4 q4 = *(const float4*)(queries + base);
      float4 o4;
      o4.x = q4.x * m4.x + (1.f - m4.x) * (O[g][cg][0] * li4[0]);
      o4.y = q4.y * m4.y + (1.f - m4.y) * (O[g][cg][1] * li4[1]);
      o4.z = q4.z * m4.z + (1.f - m4.z) * (O[g][cg][2] * li4[2]);
      o4.w = q4.w * m4.w + (1.f - m4.w) * (O[g][cg][3] * li4[3]);
      *(float4*)(out + base) = o4;
    }
  }
}

extern "C" void kernel_launch(void* const* d_in, const int* in_sizes, int n_in,
                              void* d_out, int out_size, void* d_ws, size_t ws_size,
                              hipStream_t stream) {
  const float* queries = (const float*)d_in[0];
  const float* keys    = (const float*)d_in[1];
  const float* mask    = (const float*)d_in[2];
  const float* Wq = (const float*)d_in[3];
  const float* bq = (const float*)d_in[4];
  const float* Wk = (const float*)d_in[5];
  const float* bk = (const float*)d_in[6];
  const float* Wv = (const float*)d_in[7];
  const float* bv = (const float*)d_in[8];
  float* out = (float*)d_out;

  const size_t elems = (size_t)8 * NDIM * CDIM;
  _Float16* Qh = (_Float16*)d_ws;
  _Float16* Kh = Qh + elems;
  _Float16* Vh = Kh + elems;
  _Float16* Wc = Vh + elems;   // 3*65536 fp16

  cast_w_kernel<<<dim3(192), 256, 0, stream>>>(Wq, Wk, Wv, Wc);
  proj_kernel<<<dim3(32, 1, 24), 256, 0, stream>>>(
      queries, keys, Wc, bq, bk, bv, Qh, Kh, Vh);
  attn_kernel<<<dim3(512), 256, 0, stream>>>(
      queries, mask, Qh, Kh, Vh, out);
}

// Round 7
// 331.712 us; speedup vs baseline: 1.6154x; 1.6154x over previous
//
#include <hip/hip_runtime.h>

typedef __attribute__((ext_vector_type(8))) _Float16 half8;
typedef __attribute__((ext_vector_type(4))) _Float16 half4;
typedef __attribute__((ext_vector_type(4))) float f32x4;

#define CDIM 256
#define NDIM 4096
#define MFMAH(a, b, c) __builtin_amdgcn_mfma_f32_16x16x32_f16((a), (b), (c), 0, 0, 0)

// ---------------------------------------------------------------------------
// Cast W matrices to fp16 once per launch (L2-resident afterwards).
// ---------------------------------------------------------------------------
__global__ void cast_w_kernel(const float* __restrict__ Wq,
                              const float* __restrict__ Wk,
                              const float* __restrict__ Wv,
                              _Float16* __restrict__ Wc) {
  int t = blockIdx.x * 256 + threadIdx.x;      // 49152 float4 groups total
  int mat = t >> 14;                            // /16384
  int idx = (t & 16383) * 4;
  const float* W = (mat == 0) ? Wq : (mat == 1 ? Wk : Wv);
  float4 w = *(const float4*)(W + idx);
  half4 h = {(_Float16)w.x, (_Float16)w.y, (_Float16)w.z, (_Float16)w.w};
  *(half4*)(Wc + mat * 65536 + idx) = h;
}

// ---------------------------------------------------------------------------
// Projection (round-5 proven version): Y[b,o,n] = sum_c W[o,c] X[b,c,n] + b[o]
// n-tile 128, full o (256). X staged once; W-frags direct from global fp16.
// Q,K -> [b][n][c]; V -> [b][c][n].
// ---------------------------------------------------------------------------
__global__ __launch_bounds__(256, 2) void proj_kernel(
    const float* __restrict__ queries, const float* __restrict__ keys,
    const _Float16* __restrict__ Wc,
    const float* __restrict__ bq, const float* __restrict__ bk,
    const float* __restrict__ bv,
    _Float16* __restrict__ Qh, _Float16* __restrict__ Kh,
    _Float16* __restrict__ Vh)
{
  const int z = blockIdx.z, p = z >> 3, b = z & 7;
  const float* __restrict__ X = (p == 0) ? queries : keys;
  const _Float16* __restrict__ W = Wc + p * 65536;
  const float* __restrict__ bias = (p == 0) ? bq : (p == 1 ? bk : bv);
  const int n0 = blockIdx.x * 128;

  __shared__ __align__(16) _Float16 Xs[128][264];  // [n][c], 528 B rows

  const int tid = threadIdx.x;
  const int wv = tid >> 6, lane = tid & 63, l16 = lane & 15, quad = lane >> 4;

  // stage X tile 128n x 256c (transpose c-major global -> Xs[n][c])
#pragma unroll
  for (int it = 0; it < 32; ++it) {
    int id = tid + it * 256;
    int c = id >> 5, n4 = id & 31;
    float4 x = *(const float4*)&X[((size_t)(b * CDIM + c)) * NDIM + n0 + n4 * 4];
    Xs[n4 * 4 + 0][c] = (_Float16)x.x;
    Xs[n4 * 4 + 1][c] = (_Float16)x.y;
    Xs[n4 * 4 + 2][c] = (_Float16)x.z;
    Xs[n4 * 4 + 3][c] = (_Float16)x.w;
  }
  __syncthreads();

  f32x4 acc[4][8];
#pragma unroll
  for (int og = 0; og < 4; ++og)
#pragma unroll
    for (int ng = 0; ng < 8; ++ng) acc[og][ng] = (f32x4){0.f, 0.f, 0.f, 0.f};

#pragma unroll
  for (int kc = 0; kc < 8; ++kc) {
    half8 wf[4], xf[8];
#pragma unroll
    for (int og = 0; og < 4; ++og)
      wf[og] = *(const half8*)(W + (wv * 64 + og * 16 + l16) * CDIM + kc * 32 + quad * 8);
#pragma unroll
    for (int ng = 0; ng < 8; ++ng)
      xf[ng] = *(const half8*)&Xs[ng * 16 + l16][kc * 32 + quad * 8];
#pragma unroll
    for (int og = 0; og < 4; ++og)
#pragma unroll
      for (int ng = 0; ng < 8; ++ng)
        acc[og][ng] = MFMAH(wf[og], xf[ng], acc[og][ng]);
  }

  // epilogue: D rows = o (quad*4+r), cols = n (l16)
#pragma unroll
  for (int og = 0; og < 4; ++og) {
    float4 b4 = *(const float4*)&bias[wv * 64 + og * 16 + quad * 4];
#pragma unroll
    for (int ng = 0; ng < 8; ++ng) {
      const int n = n0 + ng * 16 + l16;
      if (p == 2) {
#pragma unroll
        for (int r = 0; r < 4; ++r) {
          int o = wv * 64 + og * 16 + quad * 4 + r;
          float y = acc[og][ng][r] + ((const float*)&b4)[r];
          Vh[((size_t)(b * CDIM + o)) * NDIM + n] = (_Float16)y;
        }
      } else {
        half4 h4;
#pragma unroll
        for (int r = 0; r < 4; ++r)
          h4[r] = (_Float16)(acc[og][ng][r] + ((const float*)&b4)[r]);
        size_t idx = ((size_t)(b * NDIM + n)) * CDIM + wv * 64 + og * 16 + quad * 4;
        if (p == 0) *(half4*)&Qh[idx] = h4;
        else        *(half4*)&Kh[idx] = h4;
      }
    }
  }
}

// ---------------------------------------------------------------------------
// Flash attention (round-5 QK/softmax structure). Changes:
//   - V read DIRECTLY from global into regs (L2-resident, 16x64B segments);
//     Vs LDS array + its staging/reads deleted.
//   - Ps/Al double-buffered -> loop-top barrier removed (2 barriers/jt).
// ---------------------------------------------------------------------------
__global__ __launch_bounds__(256, 2) void attn_kernel(
    const float* __restrict__ queries, const float* __restrict__ mask,
    const _Float16* __restrict__ Qh, const _Float16* __restrict__ Kh,
    const _Float16* __restrict__ Vh, float* __restrict__ out)
{
  const int blk = blockIdx.x, b = blk & 7, it = blk >> 3;  // b=blk&7: XCD L2 locality
  const int i0 = it * 64;

  __shared__ __align__(16) _Float16 Ks[64][264];    // [j][c]  33792 B
  __shared__ __align__(16) _Float16 Ps[2][64][72];  // [i][j]  18432 B (dbuf)
  __shared__ __align__(16) float Al[2][64];         // alpha per i-row (dbuf)
  __shared__ __align__(16) float Li[64];            // 1/l per i-row

  const int tid = threadIdx.x;
  const int wv = tid >> 6, lane = tid & 63, l16 = lane & 15, quad = lane >> 4;

  // Q fragments: B-operand layout (n=l16 -> i-row, k=quad*8+t -> c)
  half8 qf[8];
  {
    const size_t qrow = ((size_t)(b * NDIM + i0 + wv * 16 + l16)) * CDIM;
#pragma unroll
    for (int kc = 0; kc < 8; ++kc)
      qf[kc] = *(const half8*)(Qh + qrow + kc * 32 + quad * 8);
  }
  // per-lane softmax state: this lane's i-row is i0 + wv*16 + l16
  const float mval = mask[(size_t)b * NDIM + i0 + wv * 16 + l16];
  float m_run = -1e30f, l_run = 0.f;

  f32x4 O[4][4];  // [i-group][ch-group], wave's ch base = wv*64
#pragma unroll
  for (int g = 0; g < 4; ++g)
#pragma unroll
    for (int cg = 0; cg < 4; ++cg) O[g][cg] = (f32x4){0.f, 0.f, 0.f, 0.f};

  const _Float16* __restrict__ Kb = Kh + (size_t)b * NDIM * CDIM;
  const _Float16* __restrict__ Vw = Vh + ((size_t)(b * CDIM + wv * 64)) * NDIM;

  for (int jt = 0; jt < 64; ++jt) {
    const int j0 = jt * 64;
    const int pb = jt & 1;
    // stage K tile (writes race nothing: prev QK reads done before B2(jt-1))
#pragma unroll
    for (int it2 = 0; it2 < 8; ++it2) {
      int id = tid + it2 * 256;
      int j = id >> 5, c8 = id & 31;
      *(uint4*)&Ks[j][c8 * 8] = *(const uint4*)(Kb + (size_t)(j0 + j) * CDIM + c8 * 8);
    }
    // V fragments for this tile direct from global (held across QK/softmax;
    // vmcnt waited only at first PV use -> overlaps with QK compute)
    half8 vf[2][4];
#pragma unroll
    for (int kk = 0; kk < 2; ++kk)
#pragma unroll
      for (int cg = 0; cg < 4; ++cg)
        vf[kk][cg] = *(const half8*)(Vw + (size_t)(cg * 16 + l16) * NDIM + j0 + kk * 32 + quad * 8);
    __syncthreads();  // B1: Ks staged

    // S^T = K Q^T: D[m=j][n=i]; lane holds 16 j-values for i = wv*16+l16
    f32x4 s[4];
#pragma unroll
    for (int js = 0; js < 4; ++js) s[js] = (f32x4){0.f, 0.f, 0.f, 0.f};
#pragma unroll
    for (int kc = 0; kc < 8; ++kc) {
#pragma unroll
      for (int js = 0; js < 4; ++js) {
        half8 kf = *(const half8*)&Ks[js * 16 + l16][kc * 32 + quad * 8];
        s[js] = MFMAH(kf, qf[kc], s[js]);
      }
    }

    // online softmax, in-lane over 16 j-values + cross-quad (xor16, xor32)
    float a[16];
    float mx = -1e30f;
#pragma unroll
    for (int js = 0; js < 4; ++js)
#pragma unroll
      for (int r = 0; r < 4; ++r) {
        float v = s[js][r] * mval;
        a[js * 4 + r] = v;
        mx = fmaxf(mx, v);
      }
    mx = fmaxf(mx, __shfl_xor(mx, 16));
    mx = fmaxf(mx, __shfl_xor(mx, 32));
    const float mnew = fmaxf(m_run, mx);
    const float alpha = __expf(m_run - mnew);
    m_run = mnew;
    float psum = 0.f;
#pragma unroll
    for (int js = 0; js < 4; ++js) {
      float p0 = __expf(a[js * 4 + 0] - mnew);
      float p1 = __expf(a[js * 4 + 1] - mnew);
      float p2 = __expf(a[js * 4 + 2] - mnew);
      float p3 = __expf(a[js * 4 + 3] - mnew);
      psum += (p0 + p1) + (p2 + p3);
      half4 hp = {(_Float16)p0, (_Float16)p1, (_Float16)p2, (_Float16)p3};
      // P[i][j]: i = wv*16+l16, j = js*16 + quad*4 + r
      *(half4*)&Ps[pb][wv * 16 + l16][js * 16 + quad * 4] = hp;
    }
    psum += __shfl_xor(psum, 16);
    psum += __shfl_xor(psum, 32);
    l_run = l_run * alpha + psum;
    if (quad == 0) Al[pb][wv * 16 + l16] = alpha;
    __syncthreads();  // B2: Ps/Al visible

    // O rescale + O += P V  (wave covers all 64 i, channels [wv*64, +64))
    f32x4 av[4];
#pragma unroll
    for (int g = 0; g < 4; ++g) av[g] = *(const f32x4*)&Al[pb][g * 16 + quad * 4];
#pragma unroll
    for (int g = 0; g < 4; ++g)
#pragma unroll
      for (int cg = 0; cg < 4; ++cg)
#pragma unroll
        for (int r = 0; r < 4; ++r) O[g][cg][r] *= av[g][r];
#pragma unroll
    for (int kk = 0; kk < 2; ++kk) {
      half8 pa[4];
#pragma unroll
      for (int g = 0; g < 4; ++g)
        pa[g] = *(const half8*)&Ps[pb][g * 16 + l16][kk * 32 + quad * 8];
#pragma unroll
      for (int g = 0; g < 4; ++g)
#pragma unroll
        for (int cg = 0; cg < 4; ++cg)
          O[g][cg] = MFMAH(pa[g], vf[kk][cg], O[g][cg]);
    }
  }

  // publish 1/l, then blended epilogue
  if (quad == 0) Li[wv * 16 + l16] = 1.0f / l_run;
  __syncthreads();
#pragma unroll
  for (int g = 0; g < 4; ++g) {
    f32x4 li4 = *(const f32x4*)&Li[g * 16 + quad * 4];
    const int i = i0 + g * 16 + quad * 4;
    float4 m4 = *(const float4*)&mask[(size_t)b * NDIM + i];
#pragma unroll
    for (int cg = 0; cg < 4; ++cg) {
      const int c = wv * 64 + cg * 16 + l16;
      const size_t base = ((size_t)(b * CDIM + c)) * NDIM + i;
      float4 q4 = *(const float4*)(queries + base);
      float4 o4;
      o4.x = q4.x * m4.x + (1.f - m4.x) * (O[g][cg][0] * li4[0]);
      o4.y = q4.y * m4.y + (1.f - m4.y) * (O[g][cg][1] * li4[1]);
      o4.z = q4.z * m4.z + (1.f - m4.z) * (O[g][cg][2] * li4[2]);
      o4.w = q4.w * m4.w + (1.f - m4.w) * (O[g][cg][3] * li4[3]);
      *(float4*)(out + base) = o4;
    }
  }
}

extern "C" void kernel_launch(void* const* d_in, const int* in_sizes, int n_in,
                              void* d_out, int out_size, void* d_ws, size_t ws_size,
                              hipStream_t stream) {
  const float* queries = (const float*)d_in[0];
  const float* keys    = (const float*)d_in[1];
  const float* mask    = (const float*)d_in[2];
  const float* Wq = (const float*)d_in[3];
  const float* bq = (const float*)d_in[4];
  const float* Wk = (const float*)d_in[5];
  const float* bk = (const float*)d_in[6];
  const float* Wv = (const float*)d_in[7];
  const float* bv = (const float*)d_in[8];
  float* out = (float*)d_out;

  const size_t elems = (size_t)8 * NDIM * CDIM;
  _Float16* Qh = (_Float16*)d_ws;
  _Float16* Kh = Qh + elems;
  _Float16* Vh = Kh + elems;
  _Float16* Wc = Vh + elems;   // 3*65536 fp16

  cast_w_kernel<<<dim3(192), 256, 0, stream>>>(Wq, Wk, Wv, Wc);
  proj_kernel<<<dim3(32, 1, 24), 256, 0, stream>>>(
      queries, keys, Wc, bq, bk, bv, Qh, Kh, Vh);
  attn_kernel<<<dim3(512), 256, 0, stream>>>(
      queries, mask, Qh, Kh, Vh, out);
}